// Round 5
// baseline (1819148.047 us; speedup 1.0000x reference)
//
#include <hip/hip_runtime.h>
#include <hip/hip_cooperative_groups.h>
#include <stdint.h>

namespace cg = cooperative_groups;

#define NBATCH 16
#define NPTS   131072
#define NPOINT 4096
#define KWG    16                    // workgroups per batch
#define TPB    512
#define NWAVE  (TPB/64)              // 8
#define PPT    (NPTS/(KWG*TPB))      // 16 points per thread
#define SEG    (NPTS/KWG)            // 8192

typedef unsigned long long u64;
typedef unsigned int u32;

__device__ __forceinline__ u64 shfl_xor_u64(u64 v, int m) {
    u32 lo=(u32)v, hi=(u32)(v>>32);
    lo=(u32)__shfl_xor((int)lo,m,64);
    hi=(u32)__shfl_xor((int)hi,m,64);
    return ((u64)hi<<32)|lo;
}
__device__ __forceinline__ u64 shfl_u64(u64 v, int s) {
    u32 lo=(u32)v, hi=(u32)(v>>32);
    lo=(u32)__shfl((int)lo,s,64);
    hi=(u32)__shfl((int)hi,s,64);
    return ((u64)hi<<32)|lo;
}
// sc0: bypass L0/L1, served by the XCD-local L2 (intra-XCD coherent point).
__device__ __forceinline__ u64 ld64_sc0(const u64* p) {
    u64 v;
    asm volatile("global_load_dwordx2 %0, %1, off sc0\n\ts_waitcnt vmcnt(0)"
                 : "=v"(v) : "v"(p) : "memory");
    return v;
}
__device__ __forceinline__ void st64_sc0(u64* p, u64 v) {
    asm volatile("global_store_dwordx2 %0, %1, off sc0" :: "v"(p), "v"(v) : "memory");
}

// constant-index select from 16 unrolled regs (no scratch; rule #20)
#define SEL16(arr,k,out) do { \
    float a0=((k)&1)?arr[1]:arr[0];  float a1=((k)&1)?arr[3]:arr[2];   \
    float a2=((k)&1)?arr[5]:arr[4];  float a3=((k)&1)?arr[7]:arr[6];   \
    float a4=((k)&1)?arr[9]:arr[8];  float a5=((k)&1)?arr[11]:arr[10]; \
    float a6=((k)&1)?arr[13]:arr[12];float a7=((k)&1)?arr[15]:arr[14]; \
    float b0=((k)&2)?a1:a0; float b1=((k)&2)?a3:a2; \
    float b2=((k)&2)?a5:a4; float b3=((k)&2)?a7:a6; \
    float c0=((k)&4)?b1:b0; float c1=((k)&4)?b3:b2; \
    out=((k)&8)?c1:c0; } while(0)

// slot = 4 tagged u64 words: w0=[tag:15][dist:32][inv:17], w1..w3=[tag:15][coord:32][0:17]
__global__ __launch_bounds__(TPB, 2) void fps_kernel(
    const float* __restrict__ xyz, const int* __restrict__ finit,
    int* __restrict__ out, u64* ws, int coop)
{
    const int b   = blockIdx.x & 15;   // batch = low bits -> all 16 WGs on XCD b%8 (heuristic)
    const int w   = blockIdx.x >> 4;
    const int tid = threadIdx.x;
    const int lane = tid & 63;
    const int wv   = tid >> 6;

    const float* xb = xyz + (size_t)b*NPTS*3;
    const int base = w * SEG;

    u64* ring = ws;                    // [16][2][16][4]
    u64* nonc = ws + 2048;             // [16]
    u64* prob = nonc + NBATCH;         // [16][16]
    u64* verd = prob + NBATCH*KWG;     // [16][16]

    __shared__ u64   lds_keys[NWAVE];
    __shared__ float lds_cxyz[NWAVE][3];
    __shared__ float bc[3];
    __shared__ int   lds_flag;

    // ---------- one-time placement probe (L2-coherence test, not hwreg trust) ----------
    int l2s = 0;
    if (coop) {
        cg::grid_group grid = cg::this_grid();
        if (tid == 0 && w == 0)
            __hip_atomic_store(&nonc[b], __builtin_amdgcn_s_memrealtime() | 1,
                               __ATOMIC_RELAXED, __HIP_MEMORY_SCOPE_AGENT);
        grid.sync();
        u64 nb = __hip_atomic_load(&nonc[b], __ATOMIC_RELAXED, __HIP_MEMORY_SCOPE_AGENT);
        if (tid == 0)
            st64_sc0(&prob[b*KWG + w], nb ^ (0x9E3779B97F4A7C15ull * (u64)(w + 1)));
        bool seen = true;
        if (wv == 0 && lane < KWG) {
            u64 want = nb ^ (0x9E3779B97F4A7C15ull * (u64)(lane + 1));
            u64 t0 = __builtin_amdgcn_s_memrealtime();
            seen = false;
            while (!seen) {
                if (ld64_sc0(&prob[b*KWG + lane]) == want) { seen = true; break; }
                if (__builtin_amdgcn_s_memrealtime() - t0 > 20000ull) break;  // ~0.2ms
            }
        }
        if (wv == 0) {
            u64 bal = __ballot(seen);
            if (lane == 0)
                __hip_atomic_store(&verd[b*KWG + w], (bal == ~0ull) ? 1ull : 0ull,
                                   __ATOMIC_RELAXED, __HIP_MEMORY_SCOPE_AGENT);
        }
        grid.sync();
        if (wv == 0) {
            u64 v = __hip_atomic_load(&verd[b*KWG + (lane & 15)],
                                      __ATOMIC_RELAXED, __HIP_MEMORY_SCOPE_AGENT);
            u64 bal = __ballot(v != 0);
            l2s = (bal == ~0ull) ? 1 : 0;
            if (tid == 0) lds_flag = l2s;
        }
    } else {
        if (tid == 0) lds_flag = 0;
    }
    __syncthreads();
    const int l2all = lds_flag;
    if (wv == 0) l2s = l2all;

    // ---------- register-resident point state ----------
    float px[PPT], py[PPT], pz[PPT], pd[PPT];
    u32 inv[PPT];
    #pragma unroll
    for (int j = 0; j < PPT; ++j) {
        int idx = base + j*TPB + tid;
        px[j] = xb[(size_t)idx*3+0];
        py[j] = xb[(size_t)idx*3+1];
        pz[j] = xb[(size_t)idx*3+2];
        pd[j] = 1e10f;
        inv[j] = (u32)(NPTS-1-idx);
    }
    const int f0 = finit[b];
    if (w == 0 && tid == 0) out[b*NPOINT] = f0;
    float cx = xb[(size_t)f0*3+0];
    float cy = xb[(size_t)f0*3+1];
    float cz = xb[(size_t)f0*3+2];

    for (int t = 1; t < NPOINT; ++t) {
        // ---- pass1: distance update (exact golden form) + running max ----
        float mx = -1.0f;
        #pragma unroll
        for (int j = 0; j < PPT; ++j) {
            float dx = __fsub_rn(px[j], cx);
            float dy = __fsub_rn(py[j], cy);
            float dz = __fsub_rn(pz[j], cz);
            float d  = __fmaf_rn(dz, dz, __fmaf_rn(dy, dy, __fmul_rn(dx, dx)));
            float nd = fminf(pd[j], d);
            pd[j] = nd;
            mx = fmaxf(mx, nd);
        }
        // ---- pass2: max inv among ties == first-occurrence argmax ----
        u32 binv = 0;
        #pragma unroll
        for (int j = 0; j < PPT; ++j)
            binv = (pd[j] == mx) ? (inv[j] > binv ? inv[j] : binv) : binv;
        u64 key = ((u64)__float_as_uint(mx) << 17) | (u64)binv;
        // ---- wave butterfly ----
        #pragma unroll
        for (int m = 1; m < 64; m <<= 1) {
            u64 o = shfl_xor_u64(key, m);
            key = (o > key) ? o : key;
        }
        if (lane == 0) lds_keys[wv] = key;
        if (l2all) {   // wave-winner coords -> LDS (for coords-in-slot publish)
            int rel = (NPTS-1 - (int)(key & 0x1FFFF)) - base;  // j*TPB + tid
            int winj = rel >> 9;        // TPB=512
            int winlane = rel & 63;     // winner is in this wave
            float sx, sy, sz2;
            SEL16(px, winj, sx);
            SEL16(py, winj, sy);
            SEL16(pz, winj, sz2);
            sx  = __shfl(sx,  winlane, 64);
            sy  = __shfl(sy,  winlane, 64);
            sz2 = __shfl(sz2, winlane, 64);
            if (lane == 0) { lds_cxyz[wv][0]=sx; lds_cxyz[wv][1]=sy; lds_cxyz[wv][2]=sz2; }
        }
        __syncthreads();

        const int p = t & 1;
        if (wv == 0) {
            // block reduce over NWAVE wave-bests, carrying wave index
            u64 kb = (lane < NWAVE) ? lds_keys[lane] : 0;
            int W = lane & (NWAVE-1);
            #pragma unroll
            for (int m = 1; m < NWAVE; m <<= 1) {
                u64 o = shfl_xor_u64(kb, m);
                int oW = __shfl_xor(W, m, 64);
                if (o > kb) { kb = o; W = oW; }
            }
            u64* slotw = ring + ((((b<<1)|p)*KWG + w) << 2);
            const u64 tg = ((u64)(u32)t) << 49;
            if (lane == 0) {
                if (l2s) {
                    float wx = lds_cxyz[W][0], wy = lds_cxyz[W][1], wz = lds_cxyz[W][2];
                    u64 k0 = tg | kb;
                    u64 k1 = tg | ((u64)__float_as_uint(wx) << 17);
                    u64 k2w = tg | ((u64)__float_as_uint(wy) << 17);
                    u64 k3 = tg | ((u64)__float_as_uint(wz) << 17);
                    st64_sc0(slotw+1, k1); st64_sc0(slotw+2, k2w);
                    st64_sc0(slotw+3, k3); st64_sc0(slotw+0, k0);
                    // parachute copies (agent-visible) so pollers can never deadlock
                    __hip_atomic_store(slotw+1, k1, __ATOMIC_RELAXED, __HIP_MEMORY_SCOPE_AGENT);
                    __hip_atomic_store(slotw+2, k2w, __ATOMIC_RELAXED, __HIP_MEMORY_SCOPE_AGENT);
                    __hip_atomic_store(slotw+3, k3, __ATOMIC_RELAXED, __HIP_MEMORY_SCOPE_AGENT);
                    __hip_atomic_store(slotw+0, k0, __ATOMIC_RELAXED, __HIP_MEMORY_SCOPE_AGENT);
                } else {
                    __hip_atomic_store(slotw, tg | kb, __ATOMIC_RELAXED, __HIP_MEMORY_SCOPE_AGENT);
                }
            }
            // poll: lane l -> peer (l&15), word (l>>4)  (L2 path polls all 4 words)
            u64 g = 0;
            u64* sp = ring + ((((b<<1)|p)*KWG + (lane & 15)) << 2) + (lane >> 4);
            if (l2s) {
                int it = 0;
                for (;;) {
                    g = ld64_sc0(sp);
                    if ((g >> 49) == (u64)(u32)t) break;
                    if (++it > 4000) {   // parachute: agent-scope (never expected)
                        do { g = __hip_atomic_load(sp, __ATOMIC_RELAXED, __HIP_MEMORY_SCOPE_AGENT); }
                        while ((g >> 49) != (u64)(u32)t);
                        break;
                    }
                }
            } else if (lane < 16) {
                do { g = __hip_atomic_load(sp, __ATOMIC_RELAXED, __HIP_MEMORY_SCOPE_AGENT); }
                while ((g >> 49) != (u64)(u32)t);
            }
            // final butterfly over 16 peers (role groups reduce independently)
            u64 k2 = g; int P = lane & 15;
            #pragma unroll
            for (int m = 1; m < 16; m <<= 1) {
                u64 o = shfl_xor_u64(k2, m);
                int oP = __shfl_xor(P, m, 64);
                if (o > k2) { k2 = o; P = oP; }
            }
            int Pstar = __shfl(P, 0, 64);
            u64 Kstar = shfl_u64(k2, 0);
            int bi = (NPTS-1) - (int)(Kstar & 0x1FFFF);
            if (l2s) {
                u32 pay = (u32)(g >> 17);
                float cxn = __uint_as_float((u32)__shfl((int)pay, 16+Pstar, 64));
                float cyn = __uint_as_float((u32)__shfl((int)pay, 32+Pstar, 64));
                float czn = __uint_as_float((u32)__shfl((int)pay, 48+Pstar, 64));
                if (lane == 0) { bc[0]=cxn; bc[1]=cyn; bc[2]=czn; }
            } else {
                if (lane == 0) {
                    bc[0]=xb[(size_t)bi*3+0]; bc[1]=xb[(size_t)bi*3+1]; bc[2]=xb[(size_t)bi*3+2];
                }
            }
            if (lane == 0 && w == 0) out[b*NPOINT + t] = bi;
        }
        __syncthreads();
        cx = bc[0]; cy = bc[1]; cz = bc[2];
    }
}

extern "C" void kernel_launch(void* const* d_in, const int* in_sizes, int n_in,
                              void* d_out, int out_size, void* d_ws, size_t ws_size,
                              hipStream_t stream) {
    const float* xyz   = (const float*)d_in[0];
    const int*   finit = (const int*)d_in[1];
    int*         out   = (int*)d_out;
    u64*         ws    = (u64*)d_ws;   // ~21 KiB used; tag/nonce-checked, no init needed

    int coop = 1;
    void* args[] = { (void*)&xyz, (void*)&finit, (void*)&out, (void*)&ws, (void*)&coop };
    dim3 grid(NBATCH * KWG), block(TPB);
    if (hipLaunchCooperativeKernel((const void*)fps_kernel, grid, block, args, 0, stream)
        != hipSuccess) {
        int nc = 0;
        void* args2[] = { (void*)&xyz, (void*)&finit, (void*)&out, (void*)&ws, (void*)&nc };
        hipLaunchKernel((const void*)fps_kernel, grid, block, args2, 0, stream);
    }
}

// Round 6
// 11827.203 us; speedup vs baseline: 153.8105x; 153.8105x over previous
//
#include <hip/hip_runtime.h>
#include <stdint.h>

#define NBATCH 16
#define NPTS   131072
#define NPOINT 4096
#define KWG    16                    // workgroups per batch
#define TPB    1024
#define NWAVE  (TPB/64)              // 16
#define PPT    (NPTS/(KWG*TPB))      // 8 points per thread
#define SEG    (NPTS/KWG)            // 8192

typedef unsigned long long u64;
typedef unsigned int u32;

__device__ __forceinline__ u64 shfl_xor_u64(u64 v, int m) {
    u32 lo=(u32)v, hi=(u32)(v>>32);
    lo=(u32)__shfl_xor((int)lo,m,64);
    hi=(u32)__shfl_xor((int)hi,m,64);
    return ((u64)hi<<32)|lo;
}
__device__ __forceinline__ u64 shfl_u64(u64 v, int s) {
    u32 lo=(u32)v, hi=(u32)(v>>32);
    lo=(u32)__shfl((int)lo,s,64);
    hi=(u32)__shfl((int)hi,s,64);
    return ((u64)hi<<32)|lo;
}

// compile-time select from 8 unrolled regs (rule #20: no runtime indexing)
#define SEL8(arr,k,out) do { \
    float a0=((k)&1)?arr[1]:arr[0]; float a1=((k)&1)?arr[3]:arr[2]; \
    float a2=((k)&1)?arr[5]:arr[4]; float a3=((k)&1)?arr[7]:arr[6]; \
    float b0=((k)&2)?a1:a0; float b1=((k)&2)?a3:a2; \
    out=((k)&4)?b1:b0; } while(0)

// slot = 4 tagged u64 words in one 64B-aligned 32B block:
//   w0=[tag:15][dist_f32:32][inv:17]   w1..w3=[tag:15][coord_f32:32][0:17]
// Each word self-tagged -> no inter-word ordering needed.
// Depth-2 parity ring: producer cannot be 2 rounds ahead of any consumer.
__global__ __launch_bounds__(TPB, 4) void fps_kernel(
    const float* __restrict__ xyz, const int* __restrict__ finit,
    int* __restrict__ out, u64* __restrict__ ring)
{
    const int b    = blockIdx.x >> 4;
    const int w    = blockIdx.x & 15;
    const int tid  = threadIdx.x;
    const int lane = tid & 63;
    const int wv   = tid >> 6;

    const float* xb = xyz + (size_t)b*NPTS*3;
    const int base = w * SEG;

    // register-resident point state
    float px[PPT], py[PPT], pz[PPT], pd[PPT];
    u32 inv[PPT];
    #pragma unroll
    for (int j = 0; j < PPT; ++j) {
        int idx = base + j*TPB + tid;            // coalesced initial load
        px[j] = xb[(size_t)idx*3+0];
        py[j] = xb[(size_t)idx*3+1];
        pz[j] = xb[(size_t)idx*3+2];
        pd[j] = 1e10f;
        inv[j] = (u32)(NPTS-1-idx);
    }

    __shared__ u64   lds_keys[NWAVE];
    __shared__ float lds_cx[NWAVE], lds_cy[NWAVE], lds_cz[NWAVE];
    __shared__ float bc[3];
    __shared__ int   lds_bi;

    const int f0 = finit[b];
    if (w == 0 && tid == 0) out[b*NPOINT] = f0;
    float cx = xb[(size_t)f0*3+0];
    float cy = xb[(size_t)f0*3+1];
    float cz = xb[(size_t)f0*3+2];

    u64* bring = ring + (size_t)b * 2 * KWG * 4;   // [2 parity][16 wg][4 words]

    for (int t = 1; t < NPOINT; ++t) {
        // ---- pass1: distance update (golden fp32 form) + running max ----
        float mx = -1.0f;
        #pragma unroll
        for (int j = 0; j < PPT; ++j) {
            float dx = __fsub_rn(px[j], cx);
            float dy = __fsub_rn(py[j], cy);
            float dz = __fsub_rn(pz[j], cz);
            float d  = __fmaf_rn(dz, dz, __fmaf_rn(dy, dy, __fmul_rn(dx, dx)));
            float nd = fminf(pd[j], d);
            pd[j] = nd;
            mx = fmaxf(mx, nd);
        }
        // ---- pass2: max inv among ties (== first-occurrence argmax) ----
        u32 binv = 0;
        #pragma unroll
        for (int j = 0; j < PPT; ++j) {
            u32 cand = (inv[j] > binv) ? inv[j] : binv;
            binv = (pd[j] == mx) ? cand : binv;
        }
        // ---- wave butterfly: f32 max, then u32 inv among wave-ties ----
        float mxw = mx;
        #pragma unroll
        for (int m = 1; m < 64; m <<= 1)
            mxw = fmaxf(mxw, __uint_as_float((u32)__shfl_xor((int)__float_as_uint(mxw), m, 64)));
        u32 bv = (mx == mxw) ? binv : 0u;
        #pragma unroll
        for (int m = 1; m < 64; m <<= 1) {
            u32 o = (u32)__shfl_xor((int)bv, m, 64);
            bv = (o > bv) ? o : bv;
        }
        // ---- wave-winner coords (uniform jwin across wave) ----
        int rel  = (NPTS-1 - (int)bv) - base;   // = jwin*TPB + tid_win
        int jwin = rel >> 10;                   // TPB=1024
        int lwin = rel & 63;                    // winner lane in this wave
        float sx, sy, sz;
        SEL8(px, jwin, sx); SEL8(py, jwin, sy); SEL8(pz, jwin, sz);
        sx = __shfl(sx, lwin, 64); sy = __shfl(sy, lwin, 64); sz = __shfl(sz, lwin, 64);
        if (lane == 0) {
            lds_keys[wv] = ((u64)__float_as_uint(mxw) << 17) | (u64)bv;
            lds_cx[wv] = sx; lds_cy[wv] = sy; lds_cz[wv] = sz;
        }
        __syncthreads();

        const int p = t & 1;
        if (wv == 0) {
            // block butterfly over 16 wave-bests (every lane converges, carries W)
            u64 kb = lds_keys[lane & 15];
            int W  = lane & 15;
            #pragma unroll
            for (int m = 1; m < 16; m <<= 1) {
                u64 o  = shfl_xor_u64(kb, m);
                int oW = __shfl_xor(W, m, 64);
                if (o > kb) { kb = o; W = oW; }
            }
            const u64 tg = ((u64)(u32)t) << 49;
            float wx = lds_cx[W], wy = lds_cy[W], wz = lds_cz[W];
            // publish: lanes 0-3 store the 4 words in parallel
            u64* slotw = bring + (((p << 4) | w) << 2);
            if (lane < 4) {
                float wc = (lane == 1) ? wx : ((lane == 2) ? wy : wz);
                u64 wrd = (lane == 0) ? (tg | kb)
                                      : (tg | ((u64)__float_as_uint(wc) << 17));
                __hip_atomic_store(&slotw[lane], wrd, __ATOMIC_RELAXED,
                                   __HIP_MEMORY_SCOPE_AGENT);
            }
            // poll: lane -> peer(l&15), word(l>>4); own slot substituted locally
            const int peer = lane & 15, word = lane >> 4;
            u64 g;
            if (peer == w) {
                float wc = (word == 1) ? wx : ((word == 2) ? wy : wz);
                g = (word == 0) ? (tg | kb) : (tg | ((u64)__float_as_uint(wc) << 17));
            } else {
                u64* sp = bring + (((p << 4) | peer) << 2) + word;
                do {
                    g = __hip_atomic_load(sp, __ATOMIC_RELAXED, __HIP_MEMORY_SCOPE_AGENT);
                } while ((g >> 49) != (u64)(u32)t);
            }
            // key butterfly within each 16-lane group (group 0 = word0 = real keys)
            u64 k2 = g; int P = peer;
            #pragma unroll
            for (int m = 1; m < 16; m <<= 1) {
                u64 o  = shfl_xor_u64(k2, m);
                int oP = __shfl_xor(P, m, 64);
                if (o > k2) { k2 = o; P = oP; }
            }
            int Pstar = __shfl(P, 0, 64);
            u64 Kstar = shfl_u64(k2, 0);
            int bi = (NPTS-1) - (int)(Kstar & 0x1FFFF);
            u32 pay = (u32)(g >> 17);
            float cxn = __uint_as_float((u32)__shfl((int)pay, 16 + Pstar, 64));
            float cyn = __uint_as_float((u32)__shfl((int)pay, 32 + Pstar, 64));
            float czn = __uint_as_float((u32)__shfl((int)pay, 48 + Pstar, 64));
            if (lane == 0) {
                bc[0] = cxn; bc[1] = cyn; bc[2] = czn;
                if (w == 0) out[b*NPOINT + t] = bi;
            }
        }
        __syncthreads();
        cx = bc[0]; cy = bc[1]; cz = bc[2];
    }
}

extern "C" void kernel_launch(void* const* d_in, const int* in_sizes, int n_in,
                              void* d_out, int out_size, void* d_ws, size_t ws_size,
                              hipStream_t stream) {
    const float* xyz   = (const float*)d_in[0];
    const int*   finit = (const int*)d_in[1];
    int*         out   = (int*)d_out;
    u64*         ring  = (u64*)d_ws;   // 16*2*16*4*8 = 16 KiB; tag-checked, no init

    void* args[] = { (void*)&xyz, (void*)&finit, (void*)&out, (void*)&ring };
    dim3 grid(NBATCH * KWG), block(TPB);
    if (hipLaunchCooperativeKernel((const void*)fps_kernel, grid, block, args, 0, stream)
        != hipSuccess) {
        // 256 blocks x 16 waves, 1 block/CU -> co-resident anyway
        fps_kernel<<<grid, block, 0, stream>>>(xyz, finit, out, ring);
    }
}

// Round 7
// 9489.591 us; speedup vs baseline: 191.6993x; 1.2463x over previous
//
#include <hip/hip_runtime.h>
#include <stdint.h>

#define NBATCH 16
#define NPTS   131072
#define NPOINT 4096
#define KWG    16                    // workgroups per batch
#define TPB    1024
#define NWAVE  (TPB/64)              // 16
#define PPT    (NPTS/(KWG*TPB))      // 8 points per thread
#define SEG    (NPTS/KWG)            // 8192

typedef unsigned long long u64;
typedef unsigned int u32;

__device__ __forceinline__ u64 shfl_xor_u64(u64 v, int m) {
    u32 lo=(u32)v, hi=(u32)(v>>32);
    lo=(u32)__shfl_xor((int)lo,m,64);
    hi=(u32)__shfl_xor((int)hi,m,64);
    return ((u64)hi<<32)|lo;
}
__device__ __forceinline__ u64 shfl_u64(u64 v, int s) {
    u32 lo=(u32)v, hi=(u32)(v>>32);
    lo=(u32)__shfl((int)lo,s,64);
    hi=(u32)__shfl((int)hi,s,64);
    return ((u64)hi<<32)|lo;
}

// slot word: [tag:15][dist_f32:32][inv:17]
// ring layout: [batch][parity][16 peers] contiguous -> one poll set = 2 lines.
// Depth-2 parity ring: a WG overwrites slot[p] at round t+2 only after every
// peer consumed round t (proven R4/R6). Stale tags across graph replays are
// harmless: the trajectory is deterministic, stale value == value to be written.
__global__ __launch_bounds__(TPB, 4) void fps_kernel(
    const float* __restrict__ xyz, const int* __restrict__ finit,
    int* __restrict__ out, u64* __restrict__ ring)
{
    const int b    = blockIdx.x >> 4;
    const int w    = blockIdx.x & 15;
    const int tid  = threadIdx.x;
    const int lane = tid & 63;
    const int wv   = tid >> 6;

    const float* xb = xyz + (size_t)b*NPTS*3;
    const int base = w * SEG;

    // register-resident point state
    float px[PPT], py[PPT], pz[PPT], pd[PPT];
    u32 inv[PPT];
    #pragma unroll
    for (int j = 0; j < PPT; ++j) {
        int idx = base + j*TPB + tid;            // coalesced initial load
        px[j] = xb[(size_t)idx*3+0];
        py[j] = xb[(size_t)idx*3+1];
        pz[j] = xb[(size_t)idx*3+2];
        pd[j] = 1e10f;
        inv[j] = (u32)(NPTS-1-idx);
    }

    __shared__ u64   lds_keys[NWAVE];
    __shared__ float bc[3];

    const int f0 = finit[b];
    if (w == 0 && tid == 0) out[b*NPOINT] = f0;
    float cx = xb[(size_t)f0*3+0];
    float cy = xb[(size_t)f0*3+1];
    float cz = xb[(size_t)f0*3+2];

    u64* bring = ring + (size_t)b * 2 * KWG;     // [2 parity][16 peers]

    for (int t = 1; t < NPOINT; ++t) {
        // ---- pass1: distance update (golden fp32 form) + running max ----
        float mx = -1.0f;
        #pragma unroll
        for (int j = 0; j < PPT; ++j) {
            float dx = __fsub_rn(px[j], cx);
            float dy = __fsub_rn(py[j], cy);
            float dz = __fsub_rn(pz[j], cz);
            float d  = __fmaf_rn(dz, dz, __fmaf_rn(dy, dy, __fmul_rn(dx, dx)));
            float nd = fminf(pd[j], d);
            pd[j] = nd;
            mx = fmaxf(mx, nd);
        }
        // ---- pass2: max inv among ties (== first-occurrence argmax) ----
        u32 binv = 0;
        #pragma unroll
        for (int j = 0; j < PPT; ++j) {
            u32 cand = (inv[j] > binv) ? inv[j] : binv;
            binv = (pd[j] == mx) ? cand : binv;
        }
        // ---- wave butterflies: f32 max, then u32 inv among wave-ties ----
        float mxw = mx;
        #pragma unroll
        for (int m = 1; m < 64; m <<= 1)
            mxw = fmaxf(mxw, __uint_as_float((u32)__shfl_xor((int)__float_as_uint(mxw), m, 64)));
        u32 bv = (mx == mxw) ? binv : 0u;
        #pragma unroll
        for (int m = 1; m < 64; m <<= 1) {
            u32 o = (u32)__shfl_xor((int)bv, m, 64);
            bv = (o > bv) ? o : bv;
        }
        if (lane == 0)
            lds_keys[wv] = ((u64)__float_as_uint(mxw) << 17) | (u64)bv;
        __syncthreads();

        const int p = t & 1;
        if (wv == 0) {
            const u64 tt = (u64)(u32)t;
            const u64 tg = tt << 49;
            // block butterfly over 16 wave-bests (16-lane subgroup, all converge)
            u64 kb = lds_keys[lane & 15];
            #pragma unroll
            for (int m = 1; m < 16; m <<= 1) {
                u64 o = shfl_xor_u64(kb, m);
                kb = (o > kb) ? o : kb;
            }
            // publish own key (single store, issued before polling)
            u64* bp = bring + (p << 4);
            if (lane == 0)
                __hip_atomic_store(&bp[w], tg | kb, __ATOMIC_RELAXED,
                                   __HIP_MEMORY_SCOPE_AGENT);
            // poll: lane l -> peer l (self substituted); 2-deep pipelined
            u64 g = tg | kb;
            float sxl = 0.f, syl = 0.f, szl = 0.f;
            if (lane < 16) {
                if (lane != w) {
                    u64* sp = &bp[lane];
                    u64 ga = __hip_atomic_load(sp, __ATOMIC_RELAXED, __HIP_MEMORY_SCOPE_AGENT);
                    for (;;) {
                        u64 gb = __hip_atomic_load(sp, __ATOMIC_RELAXED, __HIP_MEMORY_SCOPE_AGENT);
                        if ((ga >> 49) == tt) { g = ga; break; }
                        ga = __hip_atomic_load(sp, __ATOMIC_RELAXED, __HIP_MEMORY_SCOPE_AGENT);
                        if ((gb >> 49) == tt) { g = gb; break; }
                    }
                }
                // speculative centroid prefetch: overlap remaining peers' polls
                int bi_l = (NPTS-1) - (int)(g & 0x1FFFF);
                sxl = xb[(size_t)bi_l*3+0];
                syl = xb[(size_t)bi_l*3+1];
                szl = xb[(size_t)bi_l*3+2];
            }
            // winner butterfly over 16 peers, carrying peer index
            u64 k2 = (lane < 16) ? g : 0;
            int P = lane & 15;
            #pragma unroll
            for (int m = 1; m < 16; m <<= 1) {
                u64 o  = shfl_xor_u64(k2, m);
                int oP = __shfl_xor(P, m, 64);
                if (o > k2) { k2 = o; P = oP; }
            }
            int Pstar = __shfl(P, 0, 64);
            u64 Kstar = shfl_u64(k2, 0);
            int bi = (NPTS-1) - (int)(Kstar & 0x1FFFF);
            float cxn = __shfl(sxl, Pstar, 64);
            float cyn = __shfl(syl, Pstar, 64);
            float czn = __shfl(szl, Pstar, 64);
            if (lane == 0) {
                bc[0] = cxn; bc[1] = cyn; bc[2] = czn;
                if (w == 0) out[b*NPOINT + t] = bi;
            }
        }
        __syncthreads();
        cx = bc[0]; cy = bc[1]; cz = bc[2];
    }
}

extern "C" void kernel_launch(void* const* d_in, const int* in_sizes, int n_in,
                              void* d_out, int out_size, void* d_ws, size_t ws_size,
                              hipStream_t stream) {
    const float* xyz   = (const float*)d_in[0];
    const int*   finit = (const int*)d_in[1];
    int*         out   = (int*)d_out;
    u64*         ring  = (u64*)d_ws;   // 16*2*16*8 = 4 KiB; tag-checked, no init

    void* args[] = { (void*)&xyz, (void*)&finit, (void*)&out, (void*)&ring };
    dim3 grid(NBATCH * KWG), block(TPB);
    if (hipLaunchCooperativeKernel((const void*)fps_kernel, grid, block, args, 0, stream)
        != hipSuccess) {
        // 256 blocks x 16 waves/WG, 1 WG/CU -> co-resident anyway
        fps_kernel<<<grid, block, 0, stream>>>(xyz, finit, out, ring);
    }
}

// Round 8
// 7813.917 us; speedup vs baseline: 232.8087x; 1.2144x over previous
//
#include <hip/hip_runtime.h>
#include <stdint.h>

#define NBATCH 16
#define NPTS   131072
#define NPOINT 4096
#define KWG    16                    // workgroups per batch
#define TPB    512
#define NWAVE  (TPB/64)              // 8
#define PPT    (NPTS/(KWG*TPB))      // 16 points per thread
#define SEG    (NPTS/KWG)            // 8192
#define SEGSH  13                    // log2(SEG)

typedef unsigned long long u64;
typedef unsigned int u32;

// ---- DPP helpers (all lanes active; bound_ctrl=1 -> 0 for invalid) ----
template<int CTRL>
__device__ __forceinline__ u32 dpp32(u32 x) {
    return (u32)__builtin_amdgcn_update_dpp(0, (int)x, CTRL, 0xf, 0xf, true);
}
__device__ __forceinline__ u32 umax_(u32 a, u32 b) { return a > b ? a : b; }

template<int CTRL>
__device__ __forceinline__ u64 dpp64max(u64 x) {
    u32 lo = dpp32<CTRL>((u32)x);
    u32 hi = dpp32<CTRL>((u32)(x >> 32));
    u64 o = ((u64)hi << 32) | lo;
    return o > x ? o : x;
}
// full-wave (64-lane) u32 max all-reduce
__device__ __forceinline__ u32 wave_umax(u32 x) {
    x = umax_(x, dpp32<0xB1>(x));    // quad_perm [1,0,3,2]  = xor1
    x = umax_(x, dpp32<0x4E>(x));    // quad_perm [2,3,0,1]  = xor2
    x = umax_(x, dpp32<0x124>(x));   // row_ror:4
    x = umax_(x, dpp32<0x128>(x));   // row_ror:8  -> each row16 all-reduced
    x = umax_(x, (u32)__builtin_amdgcn_ds_swizzle((int)x, 0x401F)); // xor16
    x = umax_(x, (u32)__shfl_xor((int)x, 32, 64));                  // xor32
    return x;
}
// row16 u64 max all-reduce (valid within each 16-lane row; rows isolated)
__device__ __forceinline__ u64 row16_umax64(u64 k) {
    k = dpp64max<0xB1>(k);
    k = dpp64max<0x4E>(k);
    k = dpp64max<0x124>(k);
    k = dpp64max<0x128>(k);
    return k;
}

// slot word: [tag:15][dist_f32_bits:32][inv:17]; ring [batch][parity][16 peers]
// Depth-2 parity ring (proven R4/R6/R7): producer reuses slot[p] at t+2 only
// after every peer consumed t. Poisoned/stale tags never match -> no init.
// Stale values across graph replays are benign: trajectory is deterministic.
__global__ __launch_bounds__(TPB, 2) void fps_kernel(
    const float* __restrict__ xyz, const int* __restrict__ finit,
    int* __restrict__ out, u64* __restrict__ ring)
{
    const int b    = blockIdx.x >> 4;
    const int w    = blockIdx.x & 15;
    const int tid  = threadIdx.x;
    const int lane = tid & 63;
    const int wv   = tid >> 6;

    const float* xb = xyz + (size_t)b * NPTS * 3;
    const int base = w * SEG;

    // register-resident point state
    float px[PPT], py[PPT], pz[PPT], pd[PPT];
    u32 inv[PPT];
    #pragma unroll
    for (int j = 0; j < PPT; ++j) {
        int idx = base + j * TPB + tid;          // coalesced initial load
        px[j] = xb[(size_t)idx * 3 + 0];
        py[j] = xb[(size_t)idx * 3 + 1];
        pz[j] = xb[(size_t)idx * 3 + 2];
        pd[j] = 1e10f;
        inv[j] = (u32)(NPTS - 1 - idx);
    }

    __shared__ u64   lds_keys[NWAVE];
    __shared__ float bc[3];

    const int f0 = finit[b];
    if (w == 0 && tid == 0) out[b * NPOINT] = f0;
    float cx = xb[(size_t)f0 * 3 + 0];
    float cy = xb[(size_t)f0 * 3 + 1];
    float cz = xb[(size_t)f0 * 3 + 2];

    u64* bp = ring + (size_t)b * 2 * KWG;        // [2 parity][16 peers]

    for (int t = 1; t < NPOINT; ++t) {
        // ---- pass1: distance update (golden fp32 form) + 4-way max trees ----
        float m0 = -1.0f, m1 = -1.0f, m2 = -1.0f, m3 = -1.0f;
        #pragma unroll
        for (int j = 0; j < PPT; ++j) {
            float dx = __fsub_rn(px[j], cx);
            float dy = __fsub_rn(py[j], cy);
            float dz = __fsub_rn(pz[j], cz);
            float d  = __fmaf_rn(dz, dz, __fmaf_rn(dy, dy, __fmul_rn(dx, dx)));
            float nd = fminf(pd[j], d);
            pd[j] = nd;
            if ((j & 3) == 0)      m0 = fmaxf(m0, nd);
            else if ((j & 3) == 1) m1 = fmaxf(m1, nd);
            else if ((j & 3) == 2) m2 = fmaxf(m2, nd);
            else                   m3 = fmaxf(m3, nd);
        }
        float mx = fmaxf(fmaxf(m0, m1), fmaxf(m2, m3));
        // dist >= 0: fp32 bits are order-isomorphic to u32 -> u32 reduces
        u32 mxb = wave_umax(__float_as_uint(mx));   // wave max (all lanes)
        // ---- pass2: max inv among wave-level ties (first-occurrence argmax) ----
        u32 b0 = 0, b1 = 0, b2 = 0, b3 = 0;
        #pragma unroll
        for (int j = 0; j < PPT; ++j) {
            bool tie = (__float_as_uint(pd[j]) == mxb);
            if ((j & 3) == 0)      b0 = tie ? umax_(b0, inv[j]) : b0;
            else if ((j & 3) == 1) b1 = tie ? umax_(b1, inv[j]) : b1;
            else if ((j & 3) == 2) b2 = tie ? umax_(b2, inv[j]) : b2;
            else                   b3 = tie ? umax_(b3, inv[j]) : b3;
        }
        u32 bv = wave_umax(umax_(umax_(b0, b1), umax_(b2, b3)));
        if (lane == 0)
            lds_keys[wv] = ((u64)mxb << 17) | (u64)bv;
        __syncthreads();

        const int p = t & 1;
        if (wv == 0) {
            const u64 tt = (u64)(u32)t;
            const u64 tg = tt << 49;
            // block reduce: 8 keys duplicated over row16, DPP all-reduce
            u64 kb = lds_keys[lane & (NWAVE - 1)];
            kb = row16_umax64(kb);                  // lanes 0-15 all hold block max
            u64* bpp = bp + (p << 4);
            if (lane == 0)
                __hip_atomic_store(&bpp[w], tg | kb, __ATOMIC_RELAXED,
                                   __HIP_MEMORY_SCOPE_AGENT);
            // poll peer(lane); self substituted; 2-deep pipelined (proven R7)
            u64 g = tg | kb;
            if (lane < 16 && lane != w) {
                u64* sp = &bpp[lane];
                u64 ga = __hip_atomic_load(sp, __ATOMIC_RELAXED, __HIP_MEMORY_SCOPE_AGENT);
                for (;;) {
                    u64 gb = __hip_atomic_load(sp, __ATOMIC_RELAXED, __HIP_MEMORY_SCOPE_AGENT);
                    if ((ga >> 49) == tt) { g = ga; break; }
                    ga = __hip_atomic_load(sp, __ATOMIC_RELAXED, __HIP_MEMORY_SCOPE_AGENT);
                    if ((gb >> 49) == tt) { g = gb; break; }
                }
            }
            // speculative coord prefetch (overlaps remaining peers' polls)
            float sxl = 0.f, syl = 0.f, szl = 0.f;
            if (lane < 16) {
                int bi_l = (NPTS - 1) - (int)(g & 0x1FFFF);
                sxl = xb[(size_t)bi_l * 3 + 0];
                syl = xb[(size_t)bi_l * 3 + 1];
                szl = xb[(size_t)bi_l * 3 + 2];
            }
            // winner over 16 peers: row16 DPP all-reduce (lanes 0-15 = row 0)
            u64 K = row16_umax64((lane < 16) ? g : 0);
            if (lane < 16) {
                int bi    = (NPTS - 1) - (int)(K & 0x1FFFF);
                int Pstar = bi >> SEGSH;            // winner's owner WG
                float cxn = __shfl(sxl, Pstar, 64);
                float cyn = __shfl(syl, Pstar, 64);
                float czn = __shfl(szl, Pstar, 64);
                if (lane == 0) {
                    bc[0] = cxn; bc[1] = cyn; bc[2] = czn;
                    if (w == 0) out[b * NPOINT + t] = bi;
                }
            }
        }
        __syncthreads();
        cx = bc[0]; cy = bc[1]; cz = bc[2];
    }
}

extern "C" void kernel_launch(void* const* d_in, const int* in_sizes, int n_in,
                              void* d_out, int out_size, void* d_ws, size_t ws_size,
                              hipStream_t stream) {
    const float* xyz   = (const float*)d_in[0];
    const int*   finit = (const int*)d_in[1];
    int*         out   = (int*)d_out;
    u64*         ring  = (u64*)d_ws;   // 16*2*16*8 = 4 KiB; tag-checked, no init

    void* args[] = { (void*)&xyz, (void*)&finit, (void*)&out, (void*)&ring };
    dim3 grid(NBATCH * KWG), block(TPB);
    if (hipLaunchCooperativeKernel((const void*)fps_kernel, grid, block, args, 0, stream)
        != hipSuccess) {
        // 256 blocks x 8 waves, 1 WG/CU -> co-resident anyway
        fps_kernel<<<grid, block, 0, stream>>>(xyz, finit, out, ring);
    }
}